// Round 1
// baseline (258.101 us; speedup 1.0000x reference)
//
#include <hip/hip_runtime.h>
#include <hip/hip_bf16.h>

#define LOG2E 1.4426950408889634f
#define LN2   0.69314718055994531f

// Tree log2-sum-exp2 of 13 values (inputs already in log2 domain).
__device__ __forceinline__ float lse13(const float (&x)[13]) {
  float m = fmaxf(fmaxf(fmaxf(fmaxf(x[0], x[1]), fmaxf(x[2], x[3])),
                        fmaxf(fmaxf(x[4], x[5]), fmaxf(x[6], x[7]))),
                  fmaxf(fmaxf(fmaxf(x[8], x[9]), fmaxf(x[10], x[11])), x[12]));
  float s = (((exp2f(x[0] - m) + exp2f(x[1] - m)) + (exp2f(x[2] - m) + exp2f(x[3] - m))) +
             ((exp2f(x[4] - m) + exp2f(x[5] - m)) + (exp2f(x[6] - m) + exp2f(x[7] - m)))) +
            (((exp2f(x[8] - m) + exp2f(x[9] - m)) + (exp2f(x[10] - m) + exp2f(x[11] - m))) +
             exp2f(x[12] - m));
  return m + log2f(s);
}

// ---------------------------------------------------------------------------
// K1: logits[r][k] = sum_h hs[r][h] * W[h][k] + b[k]
// One wave -> 4 rows. 64 lanes span 768 cols (12 each, 3x float4, coalesced).
// W^T staged in LDS [13][776]; inner read = contiguous wave-wide b128.
// ---------------------------------------------------------------------------
__global__ __launch_bounds__(256) void k1_logits(const float* __restrict__ hs,
                                                 const float* __restrict__ W,
                                                 const float* __restrict__ bias,
                                                 float* __restrict__ logits) {
  __shared__ float wt[13 * 776];
  for (int idx = threadIdx.x; idx < 13 * 768; idx += 256) {
    int h = idx / 13;
    int k = idx - h * 13;
    wt[k * 776 + h] = W[idx];  // coalesced global read, ~4-way LDS write conflict (one-time)
  }
  __syncthreads();
  const int lane = threadIdx.x & 63;
  const int wid = (blockIdx.x << 2) + (threadIdx.x >> 6);
  const int nw = gridDim.x << 2;
  const int rr = lane / 13;
  const int kk = lane - rr * 13;
  const float bmine = (lane < 52) ? bias[kk] : 0.0f;

  for (int g = wid; g < 8192; g += nw) {
    const int r0 = g << 2;
    const float* hp = hs + (size_t)r0 * 768 + (lane << 2);
    float4 h[4][3];
#pragma unroll
    for (int r = 0; r < 4; ++r)
#pragma unroll
      for (int q = 0; q < 3; ++q)
        h[r][q] = *(const float4*)(hp + r * 768 + q * 256);
    float acc[4][13];
#pragma unroll
    for (int r = 0; r < 4; ++r)
#pragma unroll
      for (int k = 0; k < 13; ++k) acc[r][k] = 0.0f;
#pragma unroll
    for (int q = 0; q < 3; ++q) {
#pragma unroll
      for (int k = 0; k < 13; ++k) {
        const float4 w = *(const float4*)&wt[k * 776 + q * 256 + (lane << 2)];
#pragma unroll
        for (int r = 0; r < 4; ++r)
          acc[r][k] += h[r][q].x * w.x + h[r][q].y * w.y + h[r][q].z * w.z + h[r][q].w * w.w;
      }
    }
    // Butterfly all-reduce of the 52 partials across the wave.
#pragma unroll
    for (int off = 32; off; off >>= 1)
#pragma unroll
      for (int r = 0; r < 4; ++r)
#pragma unroll
        for (int k = 0; k < 13; ++k)
          acc[r][k] += __shfl_xor(acc[r][k], off);
    if (lane < 52) {
      float v = acc[0][0];
#pragma unroll
      for (int r = 0; r < 4; ++r)
#pragma unroll
        for (int k = 0; k < 13; ++k)
          if (lane == r * 13 + k) v = acc[r][k];  // static-index select (all lanes hold sums)
      logits[(size_t)r0 * 13 + lane] = v + bmine;  // 208B contiguous per wave
    }
  }
}

// ---------------------------------------------------------------------------
// K2a: per (batch, chunk of 16 steps) compute the 13x13 log2-semiring product
// Q_c = M_{t0} (x) ... (x) M_{t0+nt-1},  M_t[i][j] = trans'[i][j] + em'_t[j].
// One wave per block, 3 cells per lane, no barriers needed (same-wave DS order).
// ---------------------------------------------------------------------------
__global__ __launch_bounds__(64) void k2a_chunks(const float* __restrict__ logits,
                                                 const int* __restrict__ amask,
                                                 const float* __restrict__ trans,
                                                 float* __restrict__ wsQ) {
  const int bc = blockIdx.x;
  const int b = bc >> 5;
  const int c = bc & 31;
  const int t0 = 1 + (c << 4);
  const int nt = min(16, 512 - t0);
  const int tid = threadIdx.x;
  __shared__ float trs[13 * 14];
  __shared__ float ems[16 * 14];
  __shared__ int msk[16];
  __shared__ float P[2][13 * 20];  // rows padded to 20 floats (80B, b128-aligned)

  for (int idx = tid; idx < 169; idx += 64) {
    int i = idx / 13;
    int jj = idx - i * 13;
    trs[i * 14 + jj] = trans[idx] * LOG2E;
  }
  for (int idx = tid; idx < nt * 13; idx += 64) {
    int ts = idx / 13;
    int jj = idx - ts * 13;
    ems[ts * 14 + jj] = logits[((size_t)(b << 9) + t0 + ts) * 13 + jj] * LOG2E;
  }
  if (tid < nt) msk[tid] = amask[(b << 9) + t0 + tid];
  __syncthreads();

  int cr[3], cj[3];
  bool cv[3];
#pragma unroll
  for (int s = 0; s < 3; ++s) {
    const int cell = tid + (s << 6);
    cv[s] = cell < 169;
    const int cc = cv[s] ? cell : 0;
    cr[s] = cc / 13;
    cj[s] = cc - cr[s] * 13;
  }
  float tr[3][13];
#pragma unroll
  for (int s = 0; s < 3; ++s)
#pragma unroll
    for (int i = 0; i < 13; ++i) tr[s][i] = trs[i * 14 + cj[s]];

  int cur = 0;
  bool inited = false;
  for (int ts = 0; ts < nt; ++ts) {
    if (msk[ts]) {  // block-uniform branch
      if (!inited) {
#pragma unroll
        for (int s = 0; s < 3; ++s)
          if (cv[s]) P[cur][cr[s] * 20 + cj[s]] = trs[cr[s] * 14 + cj[s]] + ems[ts * 14 + cj[s]];
        inited = true;
      } else {
#pragma unroll
        for (int s = 0; s < 3; ++s) {
          if (cv[s]) {
            const float* pr = &P[cur][cr[s] * 20];
            float x[13];
#pragma unroll
            for (int i = 0; i < 13; ++i) x[i] = pr[i] + tr[s][i];
            P[cur ^ 1][cr[s] * 20 + cj[s]] = lse13(x) + ems[ts * 14 + cj[s]];
          }
        }
        cur ^= 1;
      }
    }
  }
#pragma unroll
  for (int s = 0; s < 3; ++s) {
    if (cv[s]) {
      float v;
      if (inited) v = P[cur][cr[s] * 20 + cj[s]];
      else v = (cr[s] == cj[s]) ? 0.0f : -1e30f;  // identity (all steps masked)
      wsQ[(size_t)bc * 169 + tid + (s << 6)] = v;
    }
  }
}

// ---------------------------------------------------------------------------
// K2b: per batch — gold-path numerator + chain alpha through 32 chunk matrices.
// ---------------------------------------------------------------------------
__global__ __launch_bounds__(64) void k2b_combine(const float* __restrict__ logits,
                                                  const int* __restrict__ labels,
                                                  const int* __restrict__ amask,
                                                  const float* __restrict__ stt,
                                                  const float* __restrict__ endt,
                                                  const float* __restrict__ trans,
                                                  const float* __restrict__ wsQ,
                                                  float* __restrict__ outb) {
  const int b = blockIdx.x;
  const int lane = threadIdx.x;
  // ---- numerator ----
  float contrib = 0.0f;
  int msum = 0;
#pragma unroll
  for (int it = 0; it < 8; ++it) {
    const int t = (it << 6) + lane;
    const int base = (b << 9) + t;
    const int tag = labels[base];
    const int mk = amask[base];
    msum += mk;
    const float em = logits[(size_t)base * 13 + tag];
    if (t == 0) contrib += stt[tag] + em;
    else if (mk) contrib += trans[labels[base - 1] * 13 + tag] + em;
  }
#pragma unroll
  for (int off = 32; off; off >>= 1) {
    contrib += __shfl_xor(contrib, off);
    msum += __shfl_xor(msum, off);
  }
  const float num = contrib + endt[labels[(b << 9) + msum - 1]];
  // ---- denominator: alpha0' then 32 chunk matrices (log2 domain) ----
  const int j = (lane < 13) ? lane : 0;
  float a = (stt[j] + logits[(size_t)(b << 9) * 13 + j]) * LOG2E;
  const float* Qb = wsQ + (size_t)b * (32 * 169);
  float q[13];
#pragma unroll
  for (int i = 0; i < 13; ++i) q[i] = Qb[i * 13 + j];
  for (int c = 0; c < 32; ++c) {
    float qn[13];
    if (c + 1 < 32) {
      const float* Qn = Qb + (c + 1) * 169;
#pragma unroll
      for (int i = 0; i < 13; ++i) qn[i] = Qn[i * 13 + j];  // prefetch next chunk
    }
    float x[13];
#pragma unroll
    for (int i = 0; i < 13; ++i) {
      const float ai = __int_as_float(__builtin_amdgcn_readlane(__float_as_int(a), i));
      x[i] = ai + q[i];
    }
    a = lse13(x);
#pragma unroll
    for (int i = 0; i < 13; ++i) q[i] = qn[i];
  }
  float z = (lane < 13) ? (a + endt[lane] * LOG2E) : -1e30f;
  float mz = z;
#pragma unroll
  for (int off = 32; off; off >>= 1) mz = fmaxf(mz, __shfl_xor(mz, off));
  float ez = exp2f(z - mz);
#pragma unroll
  for (int off = 32; off; off >>= 1) ez += __shfl_xor(ez, off);
  if (lane == 0) outb[b] = num - (mz + log2f(ez)) * LN2;
}

__global__ __launch_bounds__(64) void k3_final(const float* __restrict__ outb,
                                               float* __restrict__ out) {
  float v = outb[threadIdx.x];
#pragma unroll
  for (int off = 32; off; off >>= 1) v += __shfl_xor(v, off);
  if (threadIdx.x == 0) out[0] = -v;
}

extern "C" void kernel_launch(void* const* d_in, const int* in_sizes, int n_in,
                              void* d_out, int out_size, void* d_ws, size_t ws_size,
                              hipStream_t stream) {
  const float* hs = (const float*)d_in[0];
  const int* labels = (const int*)d_in[1];
  const int* amask = (const int*)d_in[2];
  const float* W = (const float*)d_in[3];
  const float* bias = (const float*)d_in[4];
  const float* stt = (const float*)d_in[5];
  const float* endt = (const float*)d_in[6];
  const float* trans = (const float*)d_in[7];

  float* out = (float*)d_out;
  float* logits = out + 1;  // [64*512*13]
  float* wsQ = (float*)d_ws;                 // 64*32*169 floats = 1.384 MB
  float* outb = wsQ + 64 * 32 * 169 + 64;    // 64 floats, padded offset

  k1_logits<<<1024, 256, 0, stream>>>(hs, W, bias, logits);
  k2a_chunks<<<64 * 32, 64, 0, stream>>>(logits, amask, trans, wsQ);
  k2b_combine<<<64, 64, 0, stream>>>(logits, labels, amask, stt, endt, trans, wsQ, outb);
  k3_final<<<1, 64, 0, stream>>>(outb, out);
}

// Round 9
// 229.143 us; speedup vs baseline: 1.1264x; 1.1264x over previous
//
#include <hip/hip_runtime.h>
#include <hip/hip_bf16.h>

#define LOG2E 1.4426950408889634f
#define LN2   0.69314718055994531f

typedef __attribute__((ext_vector_type(8))) short short8;
typedef __attribute__((ext_vector_type(4))) float f32x4;

__device__ __forceinline__ unsigned bfbits(__bf16 x) {
  return (unsigned)__builtin_bit_cast(unsigned short, x);
}
// pack two fp32 -> 2 bf16 (RTNE) in one dword (v_cvt_pk_bf16_f32)
__device__ __forceinline__ unsigned cvt2bf(float a, float b) {
  return bfbits((__bf16)a) | (bfbits((__bf16)b) << 16);
}

// Tree log2-sum-exp2 of 13 values (inputs already in log2 domain).
__device__ __forceinline__ float lse13(const float (&x)[13]) {
  float m = fmaxf(fmaxf(fmaxf(fmaxf(x[0], x[1]), fmaxf(x[2], x[3])),
                        fmaxf(fmaxf(x[4], x[5]), fmaxf(x[6], x[7]))),
                  fmaxf(fmaxf(fmaxf(x[8], x[9]), fmaxf(x[10], x[11])), x[12]));
  float s = (((exp2f(x[0] - m) + exp2f(x[1] - m)) + (exp2f(x[2] - m) + exp2f(x[3] - m))) +
             ((exp2f(x[4] - m) + exp2f(x[5] - m)) + (exp2f(x[6] - m) + exp2f(x[7] - m)))) +
            (((exp2f(x[8] - m) + exp2f(x[9] - m)) + (exp2f(x[10] - m) + exp2f(x[11] - m))) +
             exp2f(x[12] - m));
  return m + log2f(s);
}

// ---------------------------------------------------------------------------
// K0: pack W[768][13] into bf16 hi/lo B-fragments for mfma_f32_16x16x32_bf16.
// Fragment layout: lane = g*16+n holds B[k = g*8+j][n], j=0..7 (2 bf16/dword).
// Output: pwsHi/pwsLo as [24][64] uint4 (one K=32 chunk per kk).
// Also zero-inits out0 (k2b accumulates into it).
// ---------------------------------------------------------------------------
__global__ __launch_bounds__(64) void k0_packW(const float* __restrict__ W,
                                               uint4* __restrict__ pwsHi,
                                               uint4* __restrict__ pwsLo,
                                               float* __restrict__ out0) {
  const int lane = threadIdx.x;
  const int g = lane >> 4;
  const int n = lane & 15;
  for (int kk = 0; kk < 24; ++kk) {
    unsigned hw[4], lw[4];
#pragma unroll
    for (int p = 0; p < 4; ++p) {
      const int h0 = kk * 32 + g * 8 + 2 * p;
      float v0 = (n < 13) ? W[h0 * 13 + n] : 0.0f;
      float v1 = (n < 13) ? W[(h0 + 1) * 13 + n] : 0.0f;
      __bf16 b0 = (__bf16)v0, b1 = (__bf16)v1;
      float r0 = v0 - (float)b0, r1 = v1 - (float)b1;
      hw[p] = bfbits(b0) | (bfbits(b1) << 16);
      lw[p] = cvt2bf(r0, r1);
    }
    pwsHi[kk * 64 + lane] = make_uint4(hw[0], hw[1], hw[2], hw[3]);
    pwsLo[kk * 64 + lane] = make_uint4(lw[0], lw[1], lw[2], lw[3]);
  }
  if (lane == 0) out0[0] = 0.0f;
}

// ---------------------------------------------------------------------------
// K1: logits = hs[32768x768] * W[768x13] + b via bf16 MFMA, hi/lo fp32 split.
// One wave per 16-row tile (grid 2048 = 32768/16). A-frag loaded straight from
// global in fragment layout (row = lane&15, k = (lane>>4)*8+j); W-frags from
// the k0-packed buffer (L2-resident, coalesced dwordx4). No LDS, no barriers.
// D = Ahi*Bhi + Alo*Bhi + Ahi*Blo (lo*lo term ~2^-18, dropped).
// D layout: col = lane&15, row = (lane>>4)*4 + r.
// ---------------------------------------------------------------------------
__global__ __launch_bounds__(64) void k1_logits_mfma(const float* __restrict__ hs,
                                                     const uint4* __restrict__ pwsHi,
                                                     const uint4* __restrict__ pwsLo,
                                                     const float* __restrict__ bias,
                                                     float* __restrict__ logits) {
  const int lane = threadIdx.x;
  const int g = lane >> 4;   // k-group 0..3
  const int n = lane & 15;   // A-row / D-col (valid col < 13)

  const size_t row = (size_t)blockIdx.x * 16 + n;
  const float* ap = hs + row * 768 + g * 8;
  f32x4 acc = {0.0f, 0.0f, 0.0f, 0.0f};

#pragma unroll 6
  for (int kk = 0; kk < 24; ++kk) {
    const float4 a0 = *(const float4*)(ap + kk * 32);
    const float4 a1 = *(const float4*)(ap + kk * 32 + 4);
    const uint4 wh = pwsHi[kk * 64 + lane];
    const uint4 wl = pwsLo[kk * 64 + lane];
    float v[8] = {a0.x, a0.y, a0.z, a0.w, a1.x, a1.y, a1.z, a1.w};
    unsigned hw[4], lw[4];
#pragma unroll
    for (int p = 0; p < 4; ++p) {
      float x0 = v[2 * p], x1 = v[2 * p + 1];
      __bf16 b0 = (__bf16)x0, b1 = (__bf16)x1;
      float r0 = x0 - (float)b0, r1 = x1 - (float)b1;
      hw[p] = bfbits(b0) | (bfbits(b1) << 16);
      lw[p] = cvt2bf(r0, r1);
    }
    const short8 ahi = __builtin_bit_cast(short8, make_uint4(hw[0], hw[1], hw[2], hw[3]));
    const short8 alo = __builtin_bit_cast(short8, make_uint4(lw[0], lw[1], lw[2], lw[3]));
    const short8 bhi = __builtin_bit_cast(short8, wh);
    const short8 blo = __builtin_bit_cast(short8, wl);
    acc = __builtin_amdgcn_mfma_f32_16x16x32_bf16(ahi, bhi, acc, 0, 0, 0);
    acc = __builtin_amdgcn_mfma_f32_16x16x32_bf16(alo, bhi, acc, 0, 0, 0);
    acc = __builtin_amdgcn_mfma_f32_16x16x32_bf16(ahi, blo, acc, 0, 0, 0);
  }

  if (n < 13) {
    const float bj = bias[n];
#pragma unroll
    for (int r = 0; r < 4; ++r)
      logits[((size_t)blockIdx.x * 16 + g * 4 + r) * 13 + n] = acc[r] + bj;
  }
}

// ---------------------------------------------------------------------------
// K2a: per (batch, chunk of 16 steps) compute the 13x13 log2-semiring product
// Q_c = M_{t0} (x) ... (x) M_{t0+nt-1},  M_t[i][j] = trans'[i][j] + em'_t[j].
// One wave per block, 3 cells per lane.
// ---------------------------------------------------------------------------
__global__ __launch_bounds__(64) void k2a_chunks(const float* __restrict__ logits,
                                                 const int* __restrict__ amask,
                                                 const float* __restrict__ trans,
                                                 float* __restrict__ wsQ) {
  const int bc = blockIdx.x;
  const int b = bc >> 5;
  const int c = bc & 31;
  const int t0 = 1 + (c << 4);
  const int nt = min(16, 512 - t0);
  const int tid = threadIdx.x;
  __shared__ float trs[13 * 14];
  __shared__ float ems[16 * 14];
  __shared__ int msk[16];
  __shared__ float P[2][13 * 20];

  for (int idx = tid; idx < 169; idx += 64) {
    int i = idx / 13;
    int jj = idx - i * 13;
    trs[i * 14 + jj] = trans[idx] * LOG2E;
  }
  for (int idx = tid; idx < nt * 13; idx += 64) {
    int ts = idx / 13;
    int jj = idx - ts * 13;
    ems[ts * 14 + jj] = logits[((size_t)(b << 9) + t0 + ts) * 13 + jj] * LOG2E;
  }
  if (tid < nt) msk[tid] = amask[(b << 9) + t0 + tid];
  __syncthreads();

  int cr[3], cj[3];
  bool cv[3];
#pragma unroll
  for (int s = 0; s < 3; ++s) {
    const int cell = tid + (s << 6);
    cv[s] = cell < 169;
    const int cc = cv[s] ? cell : 0;
    cr[s] = cc / 13;
    cj[s] = cc - cr[s] * 13;
  }
  float tr[3][13];
#pragma unroll
  for (int s = 0; s < 3; ++s)
#pragma unroll
    for (int i = 0; i < 13; ++i) tr[s][i] = trs[i * 14 + cj[s]];

  int cur = 0;
  bool inited = false;
  for (int ts = 0; ts < nt; ++ts) {
    if (msk[ts]) {
      if (!inited) {
#pragma unroll
        for (int s = 0; s < 3; ++s)
          if (cv[s]) P[cur][cr[s] * 20 + cj[s]] = trs[cr[s] * 14 + cj[s]] + ems[ts * 14 + cj[s]];
        inited = true;
      } else {
#pragma unroll
        for (int s = 0; s < 3; ++s) {
          if (cv[s]) {
            const float* pr = &P[cur][cr[s] * 20];
            float x[13];
#pragma unroll
            for (int i = 0; i < 13; ++i) x[i] = pr[i] + tr[s][i];
            P[cur ^ 1][cr[s] * 20 + cj[s]] = lse13(x) + ems[ts * 14 + cj[s]];
          }
        }
        cur ^= 1;
      }
    }
  }
#pragma unroll
  for (int s = 0; s < 3; ++s) {
    if (cv[s]) {
      float v;
      if (inited) v = P[cur][cr[s] * 20 + cj[s]];
      else v = (cr[s] == cj[s]) ? 0.0f : -1e30f;
      wsQ[(size_t)bc * 169 + tid + (s << 6)] = v;
    }
  }
}

// ---------------------------------------------------------------------------
// K2b: per batch — gold-path numerator + chain alpha through 32 chunk matrices,
// then atomicAdd(-llh_b) into out[0].
// ---------------------------------------------------------------------------
__global__ __launch_bounds__(64) void k2b_combine(const float* __restrict__ logits,
                                                  const int* __restrict__ labels,
                                                  const int* __restrict__ amask,
                                                  const float* __restrict__ stt,
                                                  const float* __restrict__ endt,
                                                  const float* __restrict__ trans,
                                                  const float* __restrict__ wsQ,
                                                  float* __restrict__ out0) {
  const int b = blockIdx.x;
  const int lane = threadIdx.x;
  // ---- numerator ----
  float contrib = 0.0f;
  int msum = 0;
#pragma unroll
  for (int it = 0; it < 8; ++it) {
    const int t = (it << 6) + lane;
    const int base = (b << 9) + t;
    const int tag = labels[base];
    const int mk = amask[base];
    msum += mk;
    const float em = logits[(size_t)base * 13 + tag];
    if (t == 0) contrib += stt[tag] + em;
    else if (mk) contrib += trans[labels[base - 1] * 13 + tag] + em;
  }
#pragma unroll
  for (int off = 32; off; off >>= 1) {
    contrib += __shfl_xor(contrib, off);
    msum += __shfl_xor(msum, off);
  }
  const float num = contrib + endt[labels[(b << 9) + msum - 1]];
  // ---- denominator: alpha0' then 32 chunk matrices (log2 domain) ----
  const int j = (lane < 13) ? lane : 0;
  float a = (stt[j] + logits[(size_t)(b << 9) * 13 + j]) * LOG2E;
  const float* Qb = wsQ + (size_t)b * (32 * 169);
  float q[13];
#pragma unroll
  for (int i = 0; i < 13; ++i) q[i] = Qb[i * 13 + j];
  for (int c = 0; c < 32; ++c) {
    float qn[13];
    if (c + 1 < 32) {
      const float* Qn = Qb + (c + 1) * 169;
#pragma unroll
      for (int i = 0; i < 13; ++i) qn[i] = Qn[i * 13 + j];
    }
    float x[13];
#pragma unroll
    for (int i = 0; i < 13; ++i) {
      const float ai = __int_as_float(__builtin_amdgcn_readlane(__float_as_int(a), i));
      x[i] = ai + q[i];
    }
    a = lse13(x);
#pragma unroll
    for (int i = 0; i < 13; ++i) q[i] = qn[i];
  }
  float z = (lane < 13) ? (a + endt[lane] * LOG2E) : -1e30f;
  float mz = z;
#pragma unroll
  for (int off = 32; off; off >>= 1) mz = fmaxf(mz, __shfl_xor(mz, off));
  float ez = exp2f(z - mz);
#pragma unroll
  for (int off = 32; off; off >>= 1) ez += __shfl_xor(ez, off);
  if (lane == 0) {
    const float llh = num - (mz + log2f(ez)) * LN2;
    atomicAdd(out0, -llh);
  }
}

extern "C" void kernel_launch(void* const* d_in, const int* in_sizes, int n_in,
                              void* d_out, int out_size, void* d_ws, size_t ws_size,
                              hipStream_t stream) {
  const float* hs = (const float*)d_in[0];
  const int* labels = (const int*)d_in[1];
  const int* amask = (const int*)d_in[2];
  const float* W = (const float*)d_in[3];
  const float* bias = (const float*)d_in[4];
  const float* stt = (const float*)d_in[5];
  const float* endt = (const float*)d_in[6];
  const float* trans = (const float*)d_in[7];

  float* out = (float*)d_out;
  float* logits = out + 1;  // [64*512*13]

  // d_ws layout: [24*64 uint4 hi][24*64 uint4 lo][wsQ 64*32*169 f32]
  uint4* pwsHi = (uint4*)d_ws;
  uint4* pwsLo = pwsHi + 24 * 64;
  float* wsQ = (float*)(pwsLo + 24 * 64);

  k0_packW<<<1, 64, 0, stream>>>(W, pwsHi, pwsLo, out);
  k1_logits_mfma<<<2048, 64, 0, stream>>>(hs, pwsHi, pwsLo, bias, logits);
  k2a_chunks<<<64 * 32, 64, 0, stream>>>(logits, amask, trans, wsQ);
  k2b_combine<<<64, 64, 0, stream>>>(logits, labels, amask, stt, endt, trans, wsQ, out);
}